// Round 9
// baseline (36.965 us; speedup 1.0000x reference)
//
#include <hip/hip_runtime.h>

// Problem constants (match setup_inputs)
#define BB   2
#define CC   3
#define HH   192
#define WW   192
#define LL   19
#define PADR 9
#define HWN  (HH * WW)          // 36864
#define TAPS (LL * LL)          // 361

#define PIXB  16                // pixels per block
#define NG16  (HWN / PIXB)      // 2304 groups per kb
#define TCOLS (PIXB + LL - 1)   // 34 tile cols (pixels)
#define TSLOT (LL * TCOLS * 4)  // 2584 float slots (19*34 float4)
#define NRND  11                // ceil(2584/256) staging rounds

#define GLOAD_LDS4(g, l)                                                      \
    __builtin_amdgcn_global_load_lds(                                         \
        (const __attribute__((address_space(1))) void*)(g),                   \
        (__attribute__((address_space(3))) void*)(l), 4, 0, 0)

__device__ __forceinline__ int reflect_h(int y) {
    return y < 0 ? -y : (y >= HH ? 2 * HH - 2 - y : y);
}
__device__ __forceinline__ int reflect_w(int xq) {
    return xq < 0 ? -xq : (xq >= WW ? 2 * WW - 2 - xq : xq);
}

// Fused single kernel. 256-thread block = 16 consecutive same-row pixels of
// one kb. Stage the 19x34-pixel reflected image tile (float4-packed channels
// j=0..2 -> slot n=kb+2j) directly from x via 4B global_load_lds with
// per-lane reflected SOURCE addresses (dest linear). Kernel taps read from
// GLOBAL, coalesced 64B per 16-lane group (one-shot stream, no LDS trip).
// Hot loop per tap: 1 global kv + toff b32 + tile b128 + 3 FMA.
__global__ __launch_bounds__(256, 8) void sv_blur_fused(
    const float* __restrict__ x, const float* __restrict__ kern,
    float* __restrict__ out) {
    __shared__ float4 tile[704];     // 11 rounds * 256 floats = 2816 floats
    __shared__ int    toff[TAPS];    // tap -> tile float4 offset (ki*34+kj)

    int bx  = blockIdx.x;
    int kb  = bx / NG16;
    int grp = bx % NG16;
    int p0  = grp * PIXB;
    int h   = p0 / WW, w0 = p0 % WW;   // w0 multiple of 16: no row crossing
    int tid = threadIdx.x;
    int wv  = tid >> 6;

    // ---- stage image tile from x (reflected per-lane source, linear dest) ----
#pragma unroll
    for (int r = 0; r < NRND; ++r) {
        int slot = (r << 8) + tid;
        int s    = slot < TSLOT ? slot : TSLOT - 1;   // clamp tail source
        int comp = s & 3;
        int pc   = (s >> 2) % TCOLS;
        int pr   = (s >> 2) / TCOLS;
        int oy   = reflect_h(h + pr - PADR);
        int ox   = reflect_w(w0 + pc - PADR);
        int j    = comp == 3 ? 0 : comp;              // w-slot: any safe src
        int n    = kb + BB * j;                       // n = b*CC+c slot
        GLOAD_LDS4(x + ((size_t)n * HH + oy) * WW + ox,
                   (char*)tile + (size_t)(((r << 8) + (wv << 6)) << 2));
    }
    // ---- tap offset table (strided: covers all 361 slots) ----
    for (int s = tid; s < TAPS; s += 256) {
        int ki = s / LL, kj = s % LL;
        toff[s] = ki * TCOLS + kj;
    }
    __syncthreads();

    // ---- compute: 16 lanes per pixel, kv from global ----
    int pp = tid >> 4;             // pixel 0..15
    int q  = tid & 15;             // lane in 16-group
    int p  = p0 + pp;
    const float*  kl = kern + (size_t)(kb * HWN + p) * TAPS;
    const float4* tb = tile + pp;
    float a0 = 0.f, a1 = 0.f, a2 = 0.f;
#pragma unroll
    for (int j = 0; j < 22; ++j) {     // taps q+0..q+336: always valid
        int t = q + (j << 4);
        float  kv = kl[t];
        float4 iv = tb[toff[t]];
        a0 = fmaf(kv, iv.x, a0);
        a1 = fmaf(kv, iv.y, a1);
        a2 = fmaf(kv, iv.z, a2);
    }
    {                                   // tail: t = q+352, valid for q < 9
        int t = q + 352;
        if (t < TAPS) {
            float  kv = kl[t];
            float4 iv = tb[toff[t]];
            a0 = fmaf(kv, iv.x, a0);
            a1 = fmaf(kv, iv.y, a1);
            a2 = fmaf(kv, iv.z, a2);
        }
    }
#pragma unroll
    for (int m = 8; m; m >>= 1) {
        a0 += __shfl_xor(a0, m, 64);
        a1 += __shfl_xor(a1, m, 64);
        a2 += __shfl_xor(a2, m, 64);
    }
    if (q < 3) {
        float v = q == 0 ? a0 : (q == 1 ? a1 : a2);
        out[(size_t)(kb + q * BB) * HWN + p] = v;
    }
}

extern "C" void kernel_launch(void* const* d_in, const int* in_sizes, int n_in,
                              void* d_out, int out_size, void* d_ws, size_t ws_size,
                              hipStream_t stream) {
    const float* x    = (const float*)d_in[0];
    const float* kern = (const float*)d_in[1];
    float*       out  = (float*)d_out;
    sv_blur_fused<<<BB * NG16, 256, 0, stream>>>(x, kern, out);
}

// Round 10
// 28.043 us; speedup vs baseline: 1.3182x; 1.3182x over previous
//
#include <hip/hip_runtime.h>

// Problem constants (match setup_inputs)
#define BB   2
#define CC   3
#define HH   192
#define WW   192
#define LL   19
#define PADR 9
#define HP   (HH + 2 * PADR)   // 210
#define WP   (WW + 2 * PADR)   // 210
#define HWN  (HH * WW)         // 36864
#define TAPS (LL * LL)         // 361

#define PIXB  16                 // pixels per block
#define NG16  (HWN / PIXB)       // 2304 groups per kb
#define TCOLS (PIXB + LL - 1)    // 34 tile cols (float4)
#define IF4   (LL * TCOLS)       // 646 float4 of image tile per block

#define GLOAD_LDS16(g, l)                                                     \
    __builtin_amdgcn_global_load_lds(                                         \
        (const __attribute__((address_space(1))) void*)(g),                   \
        (__attribute__((address_space(3))) void*)(l), 16, 0, 0)

// Reflect-pad + rearrange image into (kb, HP, WP, float4) where component j
// holds channel-slot n = kb + BB*j (n = b*CC + c ordering of the reference).
__global__ __launch_bounds__(256) void pad_rearrange(
    const float* __restrict__ x, float4* __restrict__ img) {
    int idx = blockIdx.x * blockDim.x + threadIdx.x;
    const int total = BB * HP * WP;
    if (idx >= total) return;
    int xw  = idx % WP;
    int tmp = idx / WP;
    int y   = tmp % HP;
    int kb  = tmp / HP;
    int oy = y - PADR;
    oy = oy < 0 ? -oy : (oy >= HH ? 2 * HH - 2 - oy : oy);
    int ox = xw - PADR;
    ox = ox < 0 ? -ox : (ox >= WW ? 2 * WW - 2 - ox : ox);
    float v[3];
#pragma unroll
    for (int j = 0; j < 3; ++j) {
        int n = kb + BB * j;  // n = b*CC + c, with n % BB == kb
        v[j] = x[((size_t)n * HH + oy) * WW + ox];
    }
    img[idx] = make_float4(v[0], v[1], v[2], 0.0f);
}

// 256-thread block = 16 consecutive same-row pixels of one kb.
// Only the image tile lives in LDS (12 KB, staged via 3 rounds of 16B
// global_load_lds from the padded buffer — R7-verified code). Kernel taps
// stream straight from global to registers (coalesced, compile-time offsets).
// Tap->tile offset tracked incrementally in registers (no toff table).
// Hot loop per iter: 1 global b32 + 1 ds_read_b128 + 3 FMA + ~5 VALU.
__global__ __launch_bounds__(256) void sv_blur16g(
    const float* __restrict__ kern, const float4* __restrict__ img,
    float* __restrict__ out) {
    __shared__ float4 tile[768];     // 3 rounds * 256 (slots >= 646 unused)

    int bx  = blockIdx.x;
    int kb  = bx / NG16;
    int grp = bx % NG16;
    int p0  = grp * PIXB;
    int h   = p0 / WW, w0 = p0 % WW;   // w0 multiple of 16: no row crossing
    int tid = threadIdx.x;
    int wv  = tid >> 6;

    // ---- stage image swath rows h..h+18, cols w0..w0+33 (R7-verified) ----
    const float4* isrc = img + ((size_t)kb * HP + h) * WP + w0;
#pragma unroll
    for (int r = 0; r < 3; ++r) {
        int li = (r << 8) + tid;
        int si = li < IF4 ? li : IF4 - 1;
        int rr = si / TCOLS, cc = si % TCOLS;
        GLOAD_LDS16(isrc + (size_t)rr * WP + cc,
                    (char*)tile + (size_t)(((r << 8) + (wv << 6)) << 4));
    }
    __syncthreads();

    // ---- compute: 16 lanes per pixel, kv from global ----
    int pp = tid >> 4;             // pixel 0..15
    int q  = tid & 15;             // lane in 16-group
    int p  = p0 + pp;
    const float*  kl = kern + (size_t)(kb * HWN + p) * TAPS + q;
    const float4* tb = tile + pp;

    // incremental tap coords for t = q + 16j: ki=t/19, kj=t%19, ioff=ki*34+kj
    int kj   = q;          // q <= 15 < 19
    int ioff = q;
    float a0 = 0.f, a1 = 0.f, a2 = 0.f;
#pragma unroll
    for (int j = 0; j < 22; ++j) {     // t = q..q+336: always < 361
        float  kv = kl[j << 4];        // base+q + 16j floats (imm offset)
        float4 iv = tb[ioff];
        a0 = fmaf(kv, iv.x, a0);
        a1 = fmaf(kv, iv.y, a1);
        a2 = fmaf(kv, iv.z, a2);
        // t += 16: kj+16 wraps past 19 iff kj >= 3
        bool wrap = kj >= 3;
        ioff += wrap ? 31 : 16;        // +34-3 on row wrap, else +16
        kj    = wrap ? kj - 3 : kj + 16;
    }
    {                                   // tail: t = q+352, valid for q < 9
        if (q < 9) {
            float  kv = kl[22 << 4];
            float4 iv = tb[ioff];
            a0 = fmaf(kv, iv.x, a0);
            a1 = fmaf(kv, iv.y, a1);
            a2 = fmaf(kv, iv.z, a2);
        }
    }
#pragma unroll
    for (int m = 8; m; m >>= 1) {
        a0 += __shfl_xor(a0, m, 64);
        a1 += __shfl_xor(a1, m, 64);
        a2 += __shfl_xor(a2, m, 64);
    }
    if (q < 3) {
        float v = q == 0 ? a0 : (q == 1 ? a1 : a2);
        out[(size_t)(kb + q * BB) * HWN + p] = v;
    }
}

// Fallback (no workspace): inline reflect, 3 scalar image loads per tap.
__global__ __launch_bounds__(256) void sv_blur_nows(
    const float* __restrict__ kern, const float* __restrict__ x,
    float* __restrict__ out) {
    int wid  = (blockIdx.x * blockDim.x + threadIdx.x) >> 6;
    int lane = threadIdx.x & 63;
    int p  = wid % HWN;
    int kb = wid / HWN;
    int h = p / WW, w = p % WW;
    const float* kbase = kern + (size_t)(kb * HWN + p) * TAPS;
    float a[3] = {0.f, 0.f, 0.f};
#pragma unroll
    for (int it = 0; it < 6; ++it) {
        int t = lane + 64 * it;
        if (t < TAPS) {
            float kv = kbase[t];
            int ki = t / LL, kj = t % LL;
            int oy = h + ki - PADR;
            oy = oy < 0 ? -oy : (oy >= HH ? 2 * HH - 2 - oy : oy);
            int ox = w + kj - PADR;
            ox = ox < 0 ? -ox : (ox >= WW ? 2 * WW - 2 - ox : ox);
#pragma unroll
            for (int j = 0; j < 3; ++j) {
                int n = kb + BB * j;
                a[j] = fmaf(kv, x[((size_t)n * HH + oy) * WW + ox], a[j]);
            }
        }
    }
#pragma unroll
    for (int m = 32; m; m >>= 1) {
        a[0] += __shfl_xor(a[0], m, 64);
        a[1] += __shfl_xor(a[1], m, 64);
        a[2] += __shfl_xor(a[2], m, 64);
    }
    if (lane == 0) {
#pragma unroll
        for (int j = 0; j < 3; ++j)
            out[(size_t)(kb + j * BB) * HWN + p] = a[j];
    }
}

extern "C" void kernel_launch(void* const* d_in, const int* in_sizes, int n_in,
                              void* d_out, int out_size, void* d_ws, size_t ws_size,
                              hipStream_t stream) {
    const float* x    = (const float*)d_in[0];
    const float* kern = (const float*)d_in[1];
    float*       out  = (float*)d_out;

    const size_t need = (size_t)BB * HP * WP * sizeof(float4);  // ~1.41 MB

    if (ws_size >= need) {
        float4* img = (float4*)d_ws;
        const int ptotal = BB * HP * WP;
        pad_rearrange<<<(ptotal + 255) / 256, 256, 0, stream>>>(x, img);
        sv_blur16g<<<BB * NG16, 256, 0, stream>>>(kern, img, out);
    } else {
        const int nwaves  = BB * HWN;
        const int nblocks = nwaves / 4;
        sv_blur_nows<<<nblocks, 256, 0, stream>>>(kern, x, out);
    }
}